// Round 14
// baseline (293.137 us; speedup 1.0000x reference)
//
#include <hip/hip_runtime.h>

// B=8 N=96 H=8 HS=32 NS=256.  bf16 MFMA 16x16x32 everywhere.
// v14: edge_update split into jtile=48 blocks of 256 threads -> four
// independent 4-wave barrier domains per CU (was two 8-wave domains);
// same VGPR band, same math, finer tail. Rest = v13.

#define DI __device__ __forceinline__

typedef float f32x4 __attribute__((ext_vector_type(4)));
typedef short bf16x8 __attribute__((ext_vector_type(8)));

DI unsigned short f2bf(float f) {
  union { float f; unsigned u; } v; v.f = f;
  return (unsigned short)((v.u + 0x7FFFu + ((v.u >> 16) & 1u)) >> 16);
}
DI float bf2f(unsigned short h) {
  union { unsigned u; float f; } v; v.u = ((unsigned)h) << 16;
  return v.f;
}

#define LDE 264            // padded bf16 row stride
#define SCALE 0.17677669529663687f   // 1/sqrt(32)

#define MFMA(A, B, C) __builtin_amdgcn_mfma_f32_16x16x32_bf16((A), (B), (C), 0, 0, 0)

// ---------------------------------------------------------------------------
// K0: pack 19 weight mats into bf16 MFMA B-fragment layout. 152 blocks.
// ---------------------------------------------------------------------------
__global__ __launch_bounds__(256)
void prep_frags(const float* __restrict__ We_w, const float* __restrict__ Wee_w,
                const float* __restrict__ EL1_w, const float* __restrict__ EL2_w,
                const float* __restrict__ NL1_w, const float* __restrict__ NL2_w,
                const float* __restrict__ Wn1_w, const float* __restrict__ Wn2_w,
                const float* __restrict__ Wn_w,
                unsigned short* __restrict__ fb)
{
  __shared__ float Wl[32 * 256];
  const int t = threadIdx.x;
  const int blk = blockIdx.x, kt = blk & 7, ms = blk >> 3;
  const float* src; unsigned short* dst; int NT, ntbase;
  if (ms < 3)       { src = We_w  + ms * 65536;        dst = fb;           NT = 48; ntbase = ms * 16; }
  else if (ms < 6)  { src = Wee_w + (ms - 3) * 65536;  dst = fb + 196608;  NT = 48; ntbase = (ms - 3) * 16; }
  else if (ms == 6) { src = EL1_w;                     dst = fb + 393216;  NT = 16; ntbase = 0; }
  else if (ms == 7) { src = EL2_w;                     dst = fb + 458752;  NT = 16; ntbase = 0; }
  else if (ms == 8) { src = NL1_w;                     dst = fb + 524288;  NT = 16; ntbase = 0; }
  else if (ms == 9) { src = NL2_w;                     dst = fb + 589824;  NT = 16; ntbase = 0; }
  else if (ms < 13) { src = Wn1_w + (ms - 10) * 65536; dst = fb + 655360;  NT = 48; ntbase = (ms - 10) * 16; }
  else if (ms < 16) { src = Wn2_w + (ms - 13) * 65536; dst = fb + 851968;  NT = 48; ntbase = (ms - 13) * 16; }
  else              { src = Wn_w  + (ms - 16) * 65536; dst = fb + 1048576; NT = 48; ntbase = (ms - 16) * 16; }
  for (int u = t; u < 32 * 64; u += 256) {
    const int r = u >> 6, c4 = (u & 63) << 2;
    *(float4*)(Wl + r * 256 + c4) = *(const float4*)(src + (kt * 32 + r) * 256 + c4);
  }
  __syncthreads();
  for (int u = t; u < 16 * 64; u += 256) {
    const int ntl = u >> 6, l = u & 63;
    const int kb = (l >> 4) << 3, c = ntl * 16 + (l & 15);
    unsigned short tmp[8];
    #pragma unroll
    for (int i = 0; i < 8; ++i) tmp[i] = f2bf(Wl[(kb + i) * 256 + c]);
    const int nt = ntbase + ntl;
    *(uint4*)(dst + ((size_t)(kt * NT + nt) * 64 + l) * 8) = *(const uint4*)tmp;
  }
}

// ---------------------------------------------------------------------------
// K1: qkv via MFMA. 48 blocks x 256 threads, 16 node rows each.
// ---------------------------------------------------------------------------
__global__ __launch_bounds__(256)
void node_qkv(const float* __restrict__ node, const unsigned short* __restrict__ WnF,
              const float* __restrict__ Wb, float* __restrict__ nQ,
              float* __restrict__ nK, float* __restrict__ nV)
{
  __shared__ unsigned short Xl[16 * LDE];
  const int t = threadIdx.x, lane = t & 63, w = t >> 6;
  const int rb = blockIdx.x, r0 = rb * 16;
  const int b = rb / 6, nbase = (rb % 6) * 16;

  for (int u = t; u < 16 * 64; u += 256) {
    const int j = u >> 6, gg = u & 63;
    const float4 v = *(const float4*)(node + (size_t)(r0 + j) * 256 + gg * 4);
    const unsigned lo = (unsigned)f2bf(v.x) | ((unsigned)f2bf(v.y) << 16);
    const unsigned hi = (unsigned)f2bf(v.z) | ((unsigned)f2bf(v.w) << 16);
    *(uint2*)(Xl + j * LDE + gg * 4) = make_uint2(lo, hi);
  }
  __syncthreads();

  const f32x4 z = {0.f, 0.f, 0.f, 0.f};
  bf16x8 xfr[8];
  #pragma unroll
  for (int kt = 0; kt < 8; ++kt)
    xfr[kt] = *(const bf16x8*)(Xl + (lane & 15) * LDE + ((lane >> 4) << 3) + kt * 32);
  f32x4 ac[12] = {z, z, z, z, z, z, z, z, z, z, z, z};
  __builtin_amdgcn_s_setprio(1);
  for (int kt = 0; kt < 8; ++kt) {
    #pragma unroll
    for (int m = 0; m < 12; ++m) {
      const int nt = w * 12 + m;
      const bf16x8 bf = *(const bf16x8*)(WnF + ((kt * 48 + nt) * 64 + lane) * 8);
      ac[m] = MFMA(xfr[kt], bf, ac[m]);
    }
  }
  __builtin_amdgcn_s_setprio(0);
  #pragma unroll
  for (int m = 0; m < 12; ++m) {
    const int colg = (w * 12 + m) * 16 + (lane & 15);
    const int q = colg >> 8, cn = colg & 255, h = cn >> 5, c = cn & 31;
    float* o = (q == 0) ? nQ : (q == 1) ? nK : nV;
    const float bv = Wb[colg];
    #pragma unroll
    for (int r = 0; r < 4; ++r) {
      const int j = ((lane >> 4) << 2) + r;
      o[((b * 8 + h) * 96 + nbase + j) * 32 + c] = ac[m][r] + bv;
    }
  }
}

// ---------------------------------------------------------------------------
// K2: fused node attention for one (b,i). 512 threads. LDS 57856 B.
// 2 barriers: stage | softmax-publish. nV folded into accB pre-barrier.
// ---------------------------------------------------------------------------
__global__ __launch_bounds__(512, 2)
void node_attn(const float* __restrict__ edge, const float* __restrict__ We_b,
               const unsigned short* __restrict__ WeF,
               const float* __restrict__ nQ, const float* __restrict__ nK,
               const float* __restrict__ nV, float* __restrict__ attw)
{
  __shared__ unsigned short Elds[96 * LDE];   // 50688 B
  __shared__ float sc[768];                   // 3072 B
  __shared__ float nQp[256];                  // 1024 B
  __shared__ float bias[768];                 // 3072 B

  const int tid = threadIdx.x, lane = tid & 63, wid = tid >> 6;
  const int b = blockIdx.x & 7, i = blockIdx.x >> 3;
  const size_t bi = (size_t)(b * 96 + i);

  if (tid < 256) nQp[tid] = nQ[((b * 8 + (tid >> 5)) * 96 + i) * 32 + (tid & 31)];
  for (int u = tid; u < 768; u += 512) bias[u] = We_b[u];

  const float* Erow = edge + bi * 24576;
  for (int u = tid; u < 96 * 64; u += 512) {
    const int j = u >> 6, g = u & 63;
    const float4 v = *(const float4*)(Erow + j * 256 + g * 4);
    const unsigned lo = (unsigned)f2bf(v.x) | ((unsigned)f2bf(v.y) << 16);
    const unsigned hi = (unsigned)f2bf(v.z) | ((unsigned)f2bf(v.w) << 16);
    *(uint2*)(Elds + j * LDE + g * 4) = make_uint2(lo, hi);
  }
  __syncthreads();                                   // bar1: E staged

  // ---- Phase A: head h = wid; 2 passes x 3 mt ----
  {
    const int h = wid;
    const unsigned short* wq0 = WeF + ((2 * h) * 64 + lane) * 8;
    const unsigned short* wq1 = WeF + ((2 * h + 1) * 64 + lane) * 8;
    const unsigned short* wk0 = WeF + ((16 + 2 * h) * 64 + lane) * 8;
    const unsigned short* wk1 = WeF + ((17 + 2 * h) * 64 + lane) * 8;
    const int c0 = h * 32 + (lane & 15), c1 = c0 + 16;
    const float qb0 = bias[c0] + nQp[c0], qb1 = bias[c1] + nQp[c1];
    const float kb0 = bias[256 + c0], kb1 = bias[256 + c1];
    for (int pass = 0; pass < 2; ++pass) {
      const f32x4 z = {0.f, 0.f, 0.f, 0.f};
      f32x4 aq0[3] = {z, z, z}, aq1[3] = {z, z, z}, ak0[3] = {z, z, z}, ak1[3] = {z, z, z};
      __builtin_amdgcn_s_setprio(1);
      for (int kt = 0; kt < 8; ++kt) {
        const bf16x8 b0 = *(const bf16x8*)(wq0 + kt * 24576);
        const bf16x8 b1 = *(const bf16x8*)(wq1 + kt * 24576);
        const bf16x8 b2 = *(const bf16x8*)(wk0 + kt * 24576);
        const bf16x8 b3 = *(const bf16x8*)(wk1 + kt * 24576);
        #pragma unroll
        for (int m = 0; m < 3; ++m) {
          const int mt = pass * 3 + m;
          const bf16x8 afr = *(const bf16x8*)(Elds + (mt * 16 + (lane & 15)) * LDE
                                              + ((lane >> 4) << 3) + kt * 32);
          aq0[m] = MFMA(afr, b0, aq0[m]);
          aq1[m] = MFMA(afr, b1, aq1[m]);
          ak0[m] = MFMA(afr, b2, ak0[m]);
          ak1[m] = MFMA(afr, b3, ak1[m]);
        }
      }
      __builtin_amdgcn_s_setprio(0);
      #pragma unroll
      for (int m = 0; m < 3; ++m) {
        const int mt = pass * 3 + m;
        float prod[4];
        #pragma unroll
        for (int r = 0; r < 4; ++r) {
          const int j = mt * 16 + ((lane >> 4) << 2) + r;
          const int g = ((b * 8 + h) * 96 + j) * 32;
          const float k0v = ak0[m][r] + kb0 + nK[g + (lane & 15)];
          const float k1v = ak1[m][r] + kb1 + nK[g + 16 + (lane & 15)];
          prod[r] = (aq0[m][r] + qb0) * k0v + (aq1[m][r] + qb1) * k1v;
        }
        #pragma unroll
        for (int mm = 1; mm < 16; mm <<= 1) {
          #pragma unroll
          for (int r = 0; r < 4; ++r) prod[r] += __shfl_xor(prod[r], mm, 64);
        }
        if ((lane & 15) == 0) {
          #pragma unroll
          for (int r = 0; r < 4; ++r)
            sc[h * 96 + mt * 16 + ((lane >> 4) << 2) + r] = prod[r];
        }
      }
    }
  }

  // ---- Phase B MFMA + nV fold (all independent of sc) ----
  const f32x4 z = {0.f, 0.f, 0.f, 0.f};
  f32x4 accB[6][2] = {{z, z}, {z, z}, {z, z}, {z, z}, {z, z}, {z, z}};
  const int col0 = wid * 16 + (lane & 15), col1 = col0 + 128;
  const int h0 = col0 >> 5, cc0 = col0 & 31;
  const int h1 = col1 >> 5, cc1 = col1 & 31;
  {
    const unsigned short* wb0 = WeF + ((32 + wid) * 64 + lane) * 8;
    const unsigned short* wb1 = WeF + ((40 + wid) * 64 + lane) * 8;
    __builtin_amdgcn_s_setprio(1);
    for (int kt = 0; kt < 8; ++kt) {
      const bf16x8 b0 = *(const bf16x8*)(wb0 + kt * 24576);
      const bf16x8 b1 = *(const bf16x8*)(wb1 + kt * 24576);
      #pragma unroll
      for (int mt = 0; mt < 6; ++mt) {
        const bf16x8 afr = *(const bf16x8*)(Elds + (mt * 16 + (lane & 15)) * LDE
                                            + ((lane >> 4) << 3) + kt * 32);
        accB[mt][0] = MFMA(afr, b0, accB[mt][0]);
        accB[mt][1] = MFMA(afr, b1, accB[mt][1]);
      }
    }
    __builtin_amdgcn_s_setprio(0);
    const float base0 = bias[512 + col0], base1 = bias[512 + col1];
    #pragma unroll
    for (int mt = 0; mt < 6; ++mt) {
      #pragma unroll
      for (int r = 0; r < 4; ++r) {
        const int j = mt * 16 + ((lane >> 4) << 2) + r;
        accB[mt][0][r] += base0 + nV[((b * 8 + h0) * 96 + j) * 32 + cc0];
        accB[mt][1][r] += base1 + nV[((b * 8 + h1) * 96 + j) * 32 + cc1];
      }
    }
  }

  // ---- softmax (wave-local) ----
  {
    const int h = wid;
    const float s0 = sc[h * 96 + lane] * SCALE;
    const float s1 = (lane < 32) ? sc[h * 96 + 64 + lane] * SCALE : -1e30f;
    float mx = fmaxf(s0, s1);
    #pragma unroll
    for (int m = 1; m < 64; m <<= 1) mx = fmaxf(mx, __shfl_xor(mx, m, 64));
    const float e0 = __expf(s0 - mx);
    const float e1 = (lane < 32) ? __expf(s1 - mx) : 0.f;
    float sm = e0 + e1;
    #pragma unroll
    for (int m = 1; m < 64; m <<= 1) sm += __shfl_xor(sm, m, 64);
    const float inv = 1.f / sm;
    sc[h * 96 + lane] = e0 * inv;
    if (lane < 32) sc[h * 96 + 64 + lane] = e1 * inv;
  }
  __syncthreads();                                   // bar2: attn published

  // ---- epilogue: nn = sum_j attn * accB ----
  {
    float nn[2] = {0.f, 0.f};
    #pragma unroll
    for (int mt = 0; mt < 6; ++mt) {
      #pragma unroll
      for (int r = 0; r < 4; ++r) {
        const int j = mt * 16 + ((lane >> 4) << 2) + r;
        nn[0] += sc[h0 * 96 + j] * accB[mt][0][r];
        nn[1] += sc[h1 * 96 + j] * accB[mt][1][r];
      }
    }
    #pragma unroll
    for (int s = 0; s < 2; ++s) {
      nn[s] += __shfl_xor(nn[s], 16, 64);
      nn[s] += __shfl_xor(nn[s], 32, 64);
    }
    if (lane < 16) {
      attw[bi * 256 + wid * 16 + lane] = nn[0];
      attw[bi * 256 + (wid + 8) * 16 + lane] = nn[1];
    }
  }
}

// ---------------------------------------------------------------------------
// K3: node tail. 96 blocks (row-tile x ps). NL1 -> NL2+LN -> one proj set.
// ---------------------------------------------------------------------------
__global__ __launch_bounds__(256)
void node_tail(const float* __restrict__ attw, const float* __restrict__ node,
               const unsigned short* __restrict__ NL1F, const float* __restrict__ B1,
               const unsigned short* __restrict__ NL2F, const float* __restrict__ B2,
               const float* __restrict__ g, const float* __restrict__ be,
               const unsigned short* __restrict__ Wn1F, const float* __restrict__ P1b,
               const unsigned short* __restrict__ Wn2F, const float* __restrict__ P2b,
               float* __restrict__ node_out,
               float* __restrict__ n1Q, float* __restrict__ n1K, float* __restrict__ n1V,
               float* __restrict__ n2Q, float* __restrict__ n2K, float* __restrict__ n2V)
{
  __shared__ unsigned short Xl[16 * LDE];     // attw -> LN out
  __shared__ unsigned short Hl[16 * LDE];     // relu hidden
  __shared__ float bb[1024];                  // B1|B2|g|be
  __shared__ float psum[4][16], psq[4][16];
  __shared__ float statm[16], statr[16];

  const int t = threadIdx.x, lane = t & 63, w = t >> 6;
  const int ps = blockIdx.x & 1, rb = blockIdx.x >> 1;
  const int r0 = rb * 16, b = rb / 6, nbase = (rb % 6) * 16;

  bb[t] = B1[t]; bb[256 + t] = B2[t]; bb[512 + t] = g[t]; bb[768 + t] = be[t];

  for (int u = t; u < 16 * 64; u += 256) {
    const int j = u >> 6, gg = u & 63;
    const float4 v = *(const float4*)(attw + (size_t)(r0 + j) * 256 + gg * 4);
    const unsigned lo = (unsigned)f2bf(v.x) | ((unsigned)f2bf(v.y) << 16);
    const unsigned hi = (unsigned)f2bf(v.z) | ((unsigned)f2bf(v.w) << 16);
    *(uint2*)(Xl + j * LDE + gg * 4) = make_uint2(lo, hi);
  }
  __syncthreads();                                   // bar1

  const f32x4 z = {0.f, 0.f, 0.f, 0.f};

  // ---- NL1 + relu -> Hl ----
  {
    f32x4 a1[4] = {z, z, z, z};
    for (int kt = 0; kt < 8; ++kt) {
      const bf16x8 afr = *(const bf16x8*)(Xl + (lane & 15) * LDE + ((lane >> 4) << 3) + kt * 32);
      #pragma unroll
      for (int p = 0; p < 4; ++p) {
        const bf16x8 bf = *(const bf16x8*)(NL1F + (((kt << 4) + (w * 4 + p)) * 64 + lane) * 8);
        a1[p] = MFMA(afr, bf, a1[p]);
      }
    }
    #pragma unroll
    for (int p = 0; p < 4; ++p) {
      const int col = (w * 4 + p) * 16 + (lane & 15);
      const float bv = bb[col];
      #pragma unroll
      for (int r = 0; r < 4; ++r) {
        const int j = ((lane >> 4) << 2) + r;
        Hl[j * LDE + col] = f2bf(fmaxf(a1[p][r] + bv, 0.f));
      }
    }
  }
  __syncthreads();                                   // bar2

  // ---- NL2 + residual + LayerNorm -> node_out + Xl ----
  float xv[4][4];
  {
    f32x4 a2[4] = {z, z, z, z};
    for (int kt = 0; kt < 8; ++kt) {
      const bf16x8 afr = *(const bf16x8*)(Hl + (lane & 15) * LDE + ((lane >> 4) << 3) + kt * 32);
      #pragma unroll
      for (int p = 0; p < 4; ++p) {
        const bf16x8 bf = *(const bf16x8*)(NL2F + (((kt << 4) + (w * 4 + p)) * 64 + lane) * 8);
        a2[p] = MFMA(afr, bf, a2[p]);
      }
    }
    #pragma unroll
    for (int p = 0; p < 4; ++p) {
      const int col = (w * 4 + p) * 16 + (lane & 15);
      const float bv = bb[256 + col];
      #pragma unroll
      for (int r = 0; r < 4; ++r) {
        const int j = ((lane >> 4) << 2) + r;
        xv[p][r] = a2[p][r] + bv + node[(size_t)(r0 + j) * 256 + col];
      }
    }
    #pragma unroll
    for (int r = 0; r < 4; ++r) {
      float s = 0.f, q = 0.f;
      #pragma unroll
      for (int p = 0; p < 4; ++p) { s += xv[p][r]; q += xv[p][r] * xv[p][r]; }
      #pragma unroll
      for (int m = 1; m < 16; m <<= 1) { s += __shfl_xor(s, m, 64); q += __shfl_xor(q, m, 64); }
      if ((lane & 15) == 0) {
        const int rl = ((lane >> 4) << 2) + r;
        psum[w][rl] = s; psq[w][rl] = q;
      }
    }
  }
  __syncthreads();                                   // bar3
  if (t < 16) {
    const float s = psum[0][t] + psum[1][t] + psum[2][t] + psum[3][t];
    const float q = psq[0][t] + psq[1][t] + psq[2][t] + psq[3][t];
    const float mean = s * (1.f / 256.f);
    statm[t] = mean;
    statr[t] = rsqrtf(q * (1.f / 256.f) - mean * mean + 1e-5f);
  }
  __syncthreads();                                   // bar4
  #pragma unroll
  for (int p = 0; p < 4; ++p) {
    const int col = (w * 4 + p) * 16 + (lane & 15);
    const float gv = bb[512 + col], bv = bb[768 + col];
    #pragma unroll
    for (int r = 0; r < 4; ++r) {
      const int j = ((lane >> 4) << 2) + r;
      const float o = (xv[p][r] - statm[j]) * statr[j] * gv + bv;
      if (ps == 0) node_out[(size_t)(r0 + j) * 256 + col] = o;
      Xl[j * LDE + col] = f2bf(o);
    }
  }
  __syncthreads();                                   // bar5

  // ---- projections for this block's ps ----
  {
    const unsigned short* WF = ps ? Wn2F : Wn1F;
    const float* pb = ps ? P2b : P1b;
    bf16x8 xfr[8];
    #pragma unroll
    for (int kt = 0; kt < 8; ++kt)
      xfr[kt] = *(const bf16x8*)(Xl + (lane & 15) * LDE + ((lane >> 4) << 3) + kt * 32);
    f32x4 ac[12] = {z, z, z, z, z, z, z, z, z, z, z, z};
    __builtin_amdgcn_s_setprio(1);
    for (int kt = 0; kt < 8; ++kt) {
      #pragma unroll
      for (int m = 0; m < 12; ++m) {
        const int nt = w * 12 + m;
        const bf16x8 bf = *(const bf16x8*)(WF + ((kt * 48 + nt) * 64 + lane) * 8);
        ac[m] = MFMA(xfr[kt], bf, ac[m]);
      }
    }
    __builtin_amdgcn_s_setprio(0);
    #pragma unroll
    for (int m = 0; m < 12; ++m) {
      const int colg = (w * 12 + m) * 16 + (lane & 15);
      const int q = colg >> 8, cn = colg & 255, h = cn >> 5, c = cn & 31;
      float* o = (q == 0) ? (ps ? n2Q : n1Q)
               : (q == 1) ? (ps ? n2K : n1K)
                          : (ps ? n2V : n1V);
      const float bv = pb[colg];
      #pragma unroll
      for (int r = 0; r < 4; ++r) {
        const int j = ((lane >> 4) << 2) + r;
        o[((b * 8 + h) * 96 + nbase + j) * 32 + c] = ac[m][r] + bv;
      }
    }
  }
}

// ---------------------------------------------------------------------------
// K5: fused edge update, jtile=48. 1536 blocks x 256 threads (4 waves).
// LDS ~34 KB -> 4 independent barrier domains per CU. LN out fp32 direct.
// ---------------------------------------------------------------------------
__global__ __launch_bounds__(256, 4)
void edge_update(const float* __restrict__ edge, const float* __restrict__ Wee_b,
                 const unsigned short* __restrict__ WeeF,
                 const unsigned short* __restrict__ EL1F,
                 const unsigned short* __restrict__ EL2F,
                 const float* __restrict__ EL1_b, const float* __restrict__ EL2_b,
                 const float* __restrict__ n1Q, const float* __restrict__ n1K, const float* __restrict__ n1V,
                 const float* __restrict__ n2Q, const float* __restrict__ n2K, const float* __restrict__ n2V,
                 const float* __restrict__ lng, const float* __restrict__ lnb,
                 float* __restrict__ edge_out)
{
  __shared__ unsigned short Elds[48 * LDE];   // 25344 B (E -> attw_e -> hidden)
  __shared__ float se[384];                   // silu [8h][48j]; later psum[4][48](192)
  __shared__ float bn1[768];                  // Wee_b + n1p; later psq[4][48](192)
  __shared__ float b12[512];                  // EL1|EL2 bias; [0..95] later stats
  __shared__ float lg[256], lb[256];

  const int tid = threadIdx.x, lane = tid & 63, w = tid >> 6;
  const int b = blockIdx.x & 7, rest = blockIdx.x >> 3;
  const int i = rest >> 1, jt = rest & 1, jbase = jt * 48;
  const size_t bi = (size_t)(b * 96 + i);

  for (int u = tid; u < 768; u += 256) {
    const int q = u >> 8, cn = u & 255, h = cn >> 5, c = cn & 31;
    const float* s = (q == 0) ? n1Q : (q == 1) ? n1K : n1V;
    bn1[u] = Wee_b[u] + s[((b * 8 + h) * 96 + i) * 32 + c];
  }
  b12[tid] = EL1_b[tid]; b12[256 + tid] = EL2_b[tid];
  lg[tid] = lng[tid]; lb[tid] = lnb[tid];

  const float* Erow = edge + bi * 24576 + jbase * 256;
  for (int u = tid; u < 48 * 64; u += 256) {
    const int j = u >> 6, g = u & 63;
    const float4 v = *(const float4*)(Erow + j * 256 + g * 4);
    const unsigned lo = (unsigned)f2bf(v.x) | ((unsigned)f2bf(v.y) << 16);
    const unsigned hi = (unsigned)f2bf(v.z) | ((unsigned)f2bf(v.w) << 16);
    *(uint2*)(Elds + j * LDE + g * 4) = make_uint2(lo, hi);
  }
  __syncthreads();                                   // bar1: E staged

  // ---- Phase A: wave w handles heads {w, w+4}; 3 mt; silu at write ----
  for (int pp = 0; pp < 2; ++pp) {
    const int h = w + (pp << 2);
    const unsigned short* wq0 = WeeF + ((2 * h) * 64 + lane) * 8;
    const unsigned short* wq1 = WeeF + ((2 * h + 1) * 64 + lane) * 8;
    const unsigned short* wk0 = WeeF + ((16 + 2 * h) * 64 + lane) * 8;
    const unsigned short* wk1 = WeeF + ((17 + 2 * h) * 64 + lane) * 8;
    const int c0 = h * 32 + (lane & 15), c1 = c0 + 16;
    const float qb0 = bn1[c0], qb1 = bn1[c1];
    const float kb0 = bn1[256 + c0], kb1 = bn1[256 + c1];
    const f32x4 z = {0.f, 0.f, 0.f, 0.f};
    f32x4 aq0[3] = {z, z, z}, aq1[3] = {z, z, z}, ak0[3] = {z, z, z}, ak1[3] = {z, z, z};
    __builtin_amdgcn_s_setprio(1);
    for (int kt = 0; kt < 8; ++kt) {
      const bf16x8 b0 = *(const bf16x8*)(wq0 + kt * 24576);
      const bf16x8 b1 = *(const bf16x8*)(wq1 + kt * 24576);
      const bf16x8 b2 = *(const bf16x8*)(wk0 + kt * 24576);
      const bf16x8 b3 = *(const bf16x8*)(wk1 + kt * 24576);
      #pragma unroll
      for (int m = 0; m < 3; ++m) {
        const bf16x8 afr = *(const bf16x8*)(Elds + (m * 16 + (lane & 15)) * LDE
                                            + ((lane >> 4) << 3) + kt * 32);
        aq0[m] = MFMA(afr, b0, aq0[m]);
        aq1[m] = MFMA(afr, b1, aq1[m]);
        ak0[m] = MFMA(afr, b2, ak0[m]);
        ak1[m] = MFMA(afr, b3, ak1[m]);
      }
    }
    __builtin_amdgcn_s_setprio(0);
    #pragma unroll
    for (int m = 0; m < 3; ++m) {
      float prod[4];
      #pragma unroll
      for (int r = 0; r < 4; ++r) {
        const int jl = m * 16 + ((lane >> 4) << 2) + r;
        const int g = ((b * 8 + h) * 96 + jbase + jl) * 32;
        const float q0v = aq0[m][r] + qb0 + n2Q[g + (lane & 15)];
        const float q1v = aq1[m][r] + qb1 + n2Q[g + 16 + (lane & 15)];
        const float k0v = ak0[m][r] + kb0 + n2K[g + (lane & 15)];
        const float k1v = ak1[m][r] + kb1 + n2K[g + 16 + (lane & 15)];
        prod[r] = q0v * k0v + q1v * k1v;
      }
      #pragma unroll
      for (int mm = 1; mm < 16; mm <<= 1) {
        #pragma unroll
        for (int r = 0; r < 4; ++r) prod[r] += __shfl_xor(prod[r], mm, 64);
      }
      if ((lane & 15) == 0) {
        #pragma unroll
        for (int r = 0; r < 4; ++r) {
          const float d = prod[r] * SCALE;
          se[h * 48 + m * 16 + ((lane >> 4) << 2) + r] = d / (1.f + __expf(-d));
        }
      }
    }
  }

  // ---- Phase B MFMA + n2V fold: wave w handles nt {32+w,36+w,40+w,44+w} ----
  const f32x4 z = {0.f, 0.f, 0.f, 0.f};
  f32x4 acc[3][4] = {{z, z, z, z}, {z, z, z, z}, {z, z, z, z}};
  int col[4], colh[4];
  #pragma unroll
  for (int c = 0; c < 4; ++c) { col[c] = (w + (c << 2)) * 16 + (lane & 15); colh[c] = col[c] >> 5; }
  {
    __builtin_amdgcn_s_setprio(1);
    for (int kt = 0; kt < 8; ++kt) {
      bf16x8 bfr[4];
      #pragma unroll
      for (int c = 0; c < 4; ++c)
        bfr[c] = *(const bf16x8*)(WeeF + (((32 + w + (c << 2)) * 64 + lane) * 8) + kt * 24576);
      #pragma unroll
      for (int m = 0; m < 3; ++m) {
        const bf16x8 afr = *(const bf16x8*)(Elds + (m * 16 + (lane & 15)) * LDE
                                            + ((lane >> 4) << 3) + kt * 32);
        #pragma unroll
        for (int c = 0; c < 4; ++c) acc[m][c] = MFMA(afr, bfr[c], acc[m][c]);
      }
    }
    __builtin_amdgcn_s_setprio(0);
    #pragma unroll
    for (int c = 0; c < 4; ++c) {
      const int cc = col[c] & 31;
      const float base = bn1[512 + col[c]];
      #pragma unroll
      for (int m = 0; m < 3; ++m) {
        #pragma unroll
        for (int r = 0; r < 4; ++r) {
          const int jl = m * 16 + ((lane >> 4) << 2) + r;
          acc[m][c][r] += base + n2V[((b * 8 + colh[c]) * 96 + jbase + jl) * 32 + cc];
        }
      }
    }
  }
  __syncthreads();                                   // bar2: se done + E reads done

  // ---- Phase B epilogue: attw_e = silu * acc, in place ----
  #pragma unroll
  for (int c = 0; c < 4; ++c) {
    #pragma unroll
    for (int m = 0; m < 3; ++m) {
      #pragma unroll
      for (int r = 0; r < 4; ++r) {
        const int jl = m * 16 + ((lane >> 4) << 2) + r;
        Elds[jl * LDE + col[c]] = f2bf(se[colh[c] * 48 + jl] * acc[m][c][r]);
      }
    }
  }
  __syncthreads();                                   // bar3: attw_e published

  // ---- EL1 + relu: wave w handles nt {w, w+4, w+8, w+12}, in place ----
  {
    #pragma unroll
    for (int m = 0; m < 3; ++m)
      #pragma unroll
      for (int c = 0; c < 4; ++c) acc[m][c] = z;
    __builtin_amdgcn_s_setprio(1);
    for (int kt = 0; kt < 8; ++kt) {
      bf16x8 bfr[4];
      #pragma unroll
      for (int c = 0; c < 4; ++c)
        bfr[c] = *(const bf16x8*)(EL1F + (((w + (c << 2)) * 64 + lane) * 8) + kt * 8192);
      #pragma unroll
      for (int m = 0; m < 3; ++m) {
        const bf16x8 afr = *(const bf16x8*)(Elds + (m * 16 + (lane & 15)) * LDE
                                            + ((lane >> 4) << 3) + kt * 32);
        #pragma unroll
        for (int c = 0; c < 4; ++c) acc[m][c] = MFMA(afr, bfr[c], acc[m][c]);
      }
    }
    __builtin_amdgcn_s_setprio(0);
    __syncthreads();                                 // bar4: attw_e reads done
    #pragma unroll
    for (int c = 0; c < 4; ++c) {
      const float bv = b12[col[c]];
      #pragma unroll
      for (int m = 0; m < 3; ++m) {
        #pragma unroll
        for (int r = 0; r < 4; ++r) {
          const int jl = m * 16 + ((lane >> 4) << 2) + r;
          Elds[jl * LDE + col[c]] = f2bf(fmaxf(acc[m][c][r] + bv, 0.f));
        }
      }
    }
  }
  __syncthreads();                                   // bar5: hidden published

  // ---- EL2 + residual + batched LayerNorm -> direct fp32 out ----
  {
    #pragma unroll
    for (int m = 0; m < 3; ++m)
      #pragma unroll
      for (int c = 0; c < 4; ++c) acc[m][c] = z;
    __builtin_amdgcn_s_setprio(1);
    for (int kt = 0; kt < 8; ++kt) {
      bf16x8 bfr[4];
      #pragma unroll
      for (int c = 0; c < 4; ++c)
        bfr[c] = *(const bf16x8*)(EL2F + (((w + (c << 2)) * 64 + lane) * 8) + kt * 8192);
      #pragma unroll
      for (int m = 0; m < 3; ++m) {
        const bf16x8 afr = *(const bf16x8*)(Elds + (m * 16 + (lane & 15)) * LDE
                                            + ((lane >> 4) << 3) + kt * 32);
        #pragma unroll
        for (int c = 0; c < 4; ++c) acc[m][c] = MFMA(afr, bfr[c], acc[m][c]);
      }
    }
    __builtin_amdgcn_s_setprio(0);
    // residual adds (regs + global only)
    #pragma unroll
    for (int c = 0; c < 4; ++c) {
      const float bv = b12[256 + col[c]];
      #pragma unroll
      for (int m = 0; m < 3; ++m) {
        #pragma unroll
        for (int r = 0; r < 4; ++r) {
          const int jl = m * 16 + ((lane >> 4) << 2) + r;
          acc[m][c][r] += bv + Erow[jl * 256 + col[c]];
        }
      }
    }
    // per-wave partials into se/bn1 ([4][48], both dead)
    #pragma unroll
    for (int m = 0; m < 3; ++m) {
      #pragma unroll
      for (int r = 0; r < 4; ++r) {
        float s = 0.f, q = 0.f;
        #pragma unroll
        for (int c = 0; c < 4; ++c) {
          s += acc[m][c][r];
          q += acc[m][c][r] * acc[m][c][r];
        }
        #pragma unroll
        for (int mm = 1; mm < 16; mm <<= 1) { s += __shfl_xor(s, mm, 64); q += __shfl_xor(q, mm, 64); }
        if ((lane & 15) == 0) {
          const int jl = m * 16 + ((lane >> 4) << 2) + r;
          se[w * 48 + jl] = s; bn1[w * 48 + jl] = q;
        }
      }
    }
    __syncthreads();                                 // bar6: partials published
    if (tid < 48) {
      float s = 0.f, q = 0.f;
      #pragma unroll
      for (int wv = 0; wv < 4; ++wv) { s += se[wv * 48 + tid]; q += bn1[wv * 48 + tid]; }
      const float mean = s * (1.f / 256.f);
      b12[tid] = mean;
      b12[48 + tid] = rsqrtf(q * (1.f / 256.f) - mean * mean + 1e-5f);
    }
    __syncthreads();                                 // bar7: stats published
    float* orow = edge_out + bi * 24576 + jbase * 256;
    #pragma unroll
    for (int c = 0; c < 4; ++c) {
      const float gv = lg[col[c]], bvv = lb[col[c]];
      #pragma unroll
      for (int m = 0; m < 3; ++m) {
        #pragma unroll
        for (int r = 0; r < 4; ++r) {
          const int jl = m * 16 + ((lane >> 4) << 2) + r;
          orow[jl * 256 + col[c]] = (acc[m][c][r] - b12[jl]) * b12[48 + jl] * gv + bvv;
        }
      }
    }
  }
}

// ---------------------------------------------------------------------------
extern "C" void kernel_launch(void* const* d_in, const int* in_sizes, int n_in,
                              void* d_out, int out_size, void* d_ws, size_t ws_size,
                              hipStream_t stream)
{
  (void)in_sizes; (void)n_in; (void)out_size; (void)ws_size;

  const float* node   = (const float*)d_in[0];
  const float* edge   = (const float*)d_in[1];
  const float* Wn_w   = (const float*)d_in[2];
  const float* Wn_b   = (const float*)d_in[3];
  const float* We_w   = (const float*)d_in[4];
  const float* We_b   = (const float*)d_in[5];
  const float* Wn1_w  = (const float*)d_in[6];
  const float* Wn1_b  = (const float*)d_in[7];
  const float* Wn2_w  = (const float*)d_in[8];
  const float* Wn2_b  = (const float*)d_in[9];
  const float* Wee_w  = (const float*)d_in[10];
  const float* Wee_b  = (const float*)d_in[11];
  const float* NL1_w  = (const float*)d_in[12];
  const float* NL1_b  = (const float*)d_in[13];
  const float* NL2_w  = (const float*)d_in[14];
  const float* NL2_b  = (const float*)d_in[15];
  const float* EL1_w  = (const float*)d_in[16];
  const float* EL1_b  = (const float*)d_in[17];
  const float* EL2_w  = (const float*)d_in[18];
  const float* EL2_b  = (const float*)d_in[19];
  const float* NLN1_g = (const float*)d_in[20];
  const float* NLN1_b = (const float*)d_in[21];
  const float* ELN1_g = (const float*)d_in[22];
  const float* ELN1_b = (const float*)d_in[23];

  float* out = (float*)d_out;
  float* node_out = out;               // [8,96,256]
  float* edge_out = out + 196608;      // [8,96,96,256]

  float* wsf = (float*)d_ws;
  float* nQ  = wsf;                float* nK  = wsf + 196608;   float* nV  = wsf + 393216;
  float* n1Q = wsf + 589824;       float* n1K = wsf + 786432;   float* n1V = wsf + 983040;
  float* n2Q = wsf + 1179648;      float* n2K = wsf + 1376256;  float* n2V = wsf + 1572864;
  float* attw = wsf + 1769472;
  unsigned short* fb   = (unsigned short*)(wsf + 1966080);
  unsigned short* WeF  = fb;                 // 196608
  unsigned short* WeeF = fb + 196608;        // 196608
  unsigned short* EL1F = fb + 393216;        // 65536
  unsigned short* EL2F = fb + 458752;        // 65536
  unsigned short* NL1F = fb + 524288;        // 65536
  unsigned short* NL2F = fb + 589824;        // 65536
  unsigned short* Wn1F = fb + 655360;        // 196608
  unsigned short* Wn2F = fb + 851968;        // 196608
  unsigned short* WnF  = fb + 1048576;       // 196608

  prep_frags<<<152, 256, 0, stream>>>(We_w, Wee_w, EL1_w, EL2_w, NL1_w, NL2_w,
                                      Wn1_w, Wn2_w, Wn_w, fb);
  node_qkv<<<48, 256, 0, stream>>>(node, WnF, Wn_b, nQ, nK, nV);
  node_attn<<<768, 512, 0, stream>>>(edge, We_b, WeF, nQ, nK, nV, attw);
  node_tail<<<96, 256, 0, stream>>>(attw, node, NL1F, NL1_b, NL2F, NL2_b,
                                    NLN1_g, NLN1_b, Wn1F, Wn1_b, Wn2F, Wn2_b,
                                    node_out, n1Q, n1K, n1V, n2Q, n2K, n2V);
  edge_update<<<1536, 256, 0, stream>>>(edge, Wee_b, WeeF, EL1F, EL2F,
                                        EL1_b, EL2_b, n1Q, n1K, n1V,
                                        n2Q, n2K, n2V, ELN1_g, ELN1_b, edge_out);
}

// Round 15
// 249.727 us; speedup vs baseline: 1.1738x; 1.1738x over previous
//
#include <hip/hip_runtime.h>

// B=8 N=96 H=8 HS=32 NS=256.  bf16 MFMA 16x16x32 everywhere.
// v15 = revert to v13 (best measured: 251.9us). v14's jtile split re-hit the
// VGPR-clamp spill + write-amplification failure mode (3rd confirmation that
// {512thr, 120 VGPR, 61KB LDS, 2 blk/CU} is the operating point).

#define DI __device__ __forceinline__

typedef float f32x4 __attribute__((ext_vector_type(4)));
typedef short bf16x8 __attribute__((ext_vector_type(8)));

DI unsigned short f2bf(float f) {
  union { float f; unsigned u; } v; v.f = f;
  return (unsigned short)((v.u + 0x7FFFu + ((v.u >> 16) & 1u)) >> 16);
}
DI float bf2f(unsigned short h) {
  union { unsigned u; float f; } v; v.u = ((unsigned)h) << 16;
  return v.f;
}

#define LDE 264            // padded bf16 row stride
#define SCALE 0.17677669529663687f   // 1/sqrt(32)

#define MFMA(A, B, C) __builtin_amdgcn_mfma_f32_16x16x32_bf16((A), (B), (C), 0, 0, 0)

// ---------------------------------------------------------------------------
// K0: pack 19 weight mats into bf16 MFMA B-fragment layout. 152 blocks.
// ---------------------------------------------------------------------------
__global__ __launch_bounds__(256)
void prep_frags(const float* __restrict__ We_w, const float* __restrict__ Wee_w,
                const float* __restrict__ EL1_w, const float* __restrict__ EL2_w,
                const float* __restrict__ NL1_w, const float* __restrict__ NL2_w,
                const float* __restrict__ Wn1_w, const float* __restrict__ Wn2_w,
                const float* __restrict__ Wn_w,
                unsigned short* __restrict__ fb)
{
  __shared__ float Wl[32 * 256];
  const int t = threadIdx.x;
  const int blk = blockIdx.x, kt = blk & 7, ms = blk >> 3;
  const float* src; unsigned short* dst; int NT, ntbase;
  if (ms < 3)       { src = We_w  + ms * 65536;        dst = fb;           NT = 48; ntbase = ms * 16; }
  else if (ms < 6)  { src = Wee_w + (ms - 3) * 65536;  dst = fb + 196608;  NT = 48; ntbase = (ms - 3) * 16; }
  else if (ms == 6) { src = EL1_w;                     dst = fb + 393216;  NT = 16; ntbase = 0; }
  else if (ms == 7) { src = EL2_w;                     dst = fb + 458752;  NT = 16; ntbase = 0; }
  else if (ms == 8) { src = NL1_w;                     dst = fb + 524288;  NT = 16; ntbase = 0; }
  else if (ms == 9) { src = NL2_w;                     dst = fb + 589824;  NT = 16; ntbase = 0; }
  else if (ms < 13) { src = Wn1_w + (ms - 10) * 65536; dst = fb + 655360;  NT = 48; ntbase = (ms - 10) * 16; }
  else if (ms < 16) { src = Wn2_w + (ms - 13) * 65536; dst = fb + 851968;  NT = 48; ntbase = (ms - 13) * 16; }
  else              { src = Wn_w  + (ms - 16) * 65536; dst = fb + 1048576; NT = 48; ntbase = (ms - 16) * 16; }
  for (int u = t; u < 32 * 64; u += 256) {
    const int r = u >> 6, c4 = (u & 63) << 2;
    *(float4*)(Wl + r * 256 + c4) = *(const float4*)(src + (kt * 32 + r) * 256 + c4);
  }
  __syncthreads();
  for (int u = t; u < 16 * 64; u += 256) {
    const int ntl = u >> 6, l = u & 63;
    const int kb = (l >> 4) << 3, c = ntl * 16 + (l & 15);
    unsigned short tmp[8];
    #pragma unroll
    for (int i = 0; i < 8; ++i) tmp[i] = f2bf(Wl[(kb + i) * 256 + c]);
    const int nt = ntbase + ntl;
    *(uint4*)(dst + ((size_t)(kt * NT + nt) * 64 + l) * 8) = *(const uint4*)tmp;
  }
}

// ---------------------------------------------------------------------------
// K1: qkv via MFMA. 48 blocks x 256 threads, 16 node rows each.
// ---------------------------------------------------------------------------
__global__ __launch_bounds__(256)
void node_qkv(const float* __restrict__ node, const unsigned short* __restrict__ WnF,
              const float* __restrict__ Wb, float* __restrict__ nQ,
              float* __restrict__ nK, float* __restrict__ nV)
{
  __shared__ unsigned short Xl[16 * LDE];
  const int t = threadIdx.x, lane = t & 63, w = t >> 6;
  const int rb = blockIdx.x, r0 = rb * 16;
  const int b = rb / 6, nbase = (rb % 6) * 16;

  for (int u = t; u < 16 * 64; u += 256) {
    const int j = u >> 6, gg = u & 63;
    const float4 v = *(const float4*)(node + (size_t)(r0 + j) * 256 + gg * 4);
    const unsigned lo = (unsigned)f2bf(v.x) | ((unsigned)f2bf(v.y) << 16);
    const unsigned hi = (unsigned)f2bf(v.z) | ((unsigned)f2bf(v.w) << 16);
    *(uint2*)(Xl + j * LDE + gg * 4) = make_uint2(lo, hi);
  }
  __syncthreads();

  const f32x4 z = {0.f, 0.f, 0.f, 0.f};
  bf16x8 xfr[8];
  #pragma unroll
  for (int kt = 0; kt < 8; ++kt)
    xfr[kt] = *(const bf16x8*)(Xl + (lane & 15) * LDE + ((lane >> 4) << 3) + kt * 32);
  f32x4 ac[12] = {z, z, z, z, z, z, z, z, z, z, z, z};
  __builtin_amdgcn_s_setprio(1);
  for (int kt = 0; kt < 8; ++kt) {
    #pragma unroll
    for (int m = 0; m < 12; ++m) {
      const int nt = w * 12 + m;
      const bf16x8 bf = *(const bf16x8*)(WnF + ((kt * 48 + nt) * 64 + lane) * 8);
      ac[m] = MFMA(xfr[kt], bf, ac[m]);
    }
  }
  __builtin_amdgcn_s_setprio(0);
  #pragma unroll
  for (int m = 0; m < 12; ++m) {
    const int colg = (w * 12 + m) * 16 + (lane & 15);
    const int q = colg >> 8, cn = colg & 255, h = cn >> 5, c = cn & 31;
    float* o = (q == 0) ? nQ : (q == 1) ? nK : nV;
    const float bv = Wb[colg];
    #pragma unroll
    for (int r = 0; r < 4; ++r) {
      const int j = ((lane >> 4) << 2) + r;
      o[((b * 8 + h) * 96 + nbase + j) * 32 + c] = ac[m][r] + bv;
    }
  }
}

// ---------------------------------------------------------------------------
// K2: fused node attention for one (b,i). 512 threads. LDS 57856 B.
// 2 barriers: stage | softmax-publish. nV folded into accB pre-barrier.
// ---------------------------------------------------------------------------
__global__ __launch_bounds__(512, 2)
void node_attn(const float* __restrict__ edge, const float* __restrict__ We_b,
               const unsigned short* __restrict__ WeF,
               const float* __restrict__ nQ, const float* __restrict__ nK,
               const float* __restrict__ nV, float* __restrict__ attw)
{
  __shared__ unsigned short Elds[96 * LDE];   // 50688 B
  __shared__ float sc[768];                   // 3072 B
  __shared__ float nQp[256];                  // 1024 B
  __shared__ float bias[768];                 // 3072 B

  const int tid = threadIdx.x, lane = tid & 63, wid = tid >> 6;
  const int b = blockIdx.x & 7, i = blockIdx.x >> 3;
  const size_t bi = (size_t)(b * 96 + i);

  if (tid < 256) nQp[tid] = nQ[((b * 8 + (tid >> 5)) * 96 + i) * 32 + (tid & 31)];
  for (int u = tid; u < 768; u += 512) bias[u] = We_b[u];

  const float* Erow = edge + bi * 24576;
  for (int u = tid; u < 96 * 64; u += 512) {
    const int j = u >> 6, g = u & 63;
    const float4 v = *(const float4*)(Erow + j * 256 + g * 4);
    const unsigned lo = (unsigned)f2bf(v.x) | ((unsigned)f2bf(v.y) << 16);
    const unsigned hi = (unsigned)f2bf(v.z) | ((unsigned)f2bf(v.w) << 16);
    *(uint2*)(Elds + j * LDE + g * 4) = make_uint2(lo, hi);
  }
  __syncthreads();                                   // bar1: E staged

  // ---- Phase A: head h = wid; 2 passes x 3 mt ----
  {
    const int h = wid;
    const unsigned short* wq0 = WeF + ((2 * h) * 64 + lane) * 8;
    const unsigned short* wq1 = WeF + ((2 * h + 1) * 64 + lane) * 8;
    const unsigned short* wk0 = WeF + ((16 + 2 * h) * 64 + lane) * 8;
    const unsigned short* wk1 = WeF + ((17 + 2 * h) * 64 + lane) * 8;
    const int c0 = h * 32 + (lane & 15), c1 = c0 + 16;
    const float qb0 = bias[c0] + nQp[c0], qb1 = bias[c1] + nQp[c1];
    const float kb0 = bias[256 + c0], kb1 = bias[256 + c1];
    for (int pass = 0; pass < 2; ++pass) {
      const f32x4 z = {0.f, 0.f, 0.f, 0.f};
      f32x4 aq0[3] = {z, z, z}, aq1[3] = {z, z, z}, ak0[3] = {z, z, z}, ak1[3] = {z, z, z};
      __builtin_amdgcn_s_setprio(1);
      for (int kt = 0; kt < 8; ++kt) {
        const bf16x8 b0 = *(const bf16x8*)(wq0 + kt * 24576);
        const bf16x8 b1 = *(const bf16x8*)(wq1 + kt * 24576);
        const bf16x8 b2 = *(const bf16x8*)(wk0 + kt * 24576);
        const bf16x8 b3 = *(const bf16x8*)(wk1 + kt * 24576);
        #pragma unroll
        for (int m = 0; m < 3; ++m) {
          const int mt = pass * 3 + m;
          const bf16x8 afr = *(const bf16x8*)(Elds + (mt * 16 + (lane & 15)) * LDE
                                              + ((lane >> 4) << 3) + kt * 32);
          aq0[m] = MFMA(afr, b0, aq0[m]);
          aq1[m] = MFMA(afr, b1, aq1[m]);
          ak0[m] = MFMA(afr, b2, ak0[m]);
          ak1[m] = MFMA(afr, b3, ak1[m]);
        }
      }
      __builtin_amdgcn_s_setprio(0);
      #pragma unroll
      for (int m = 0; m < 3; ++m) {
        const int mt = pass * 3 + m;
        float prod[4];
        #pragma unroll
        for (int r = 0; r < 4; ++r) {
          const int j = mt * 16 + ((lane >> 4) << 2) + r;
          const int g = ((b * 8 + h) * 96 + j) * 32;
          const float k0v = ak0[m][r] + kb0 + nK[g + (lane & 15)];
          const float k1v = ak1[m][r] + kb1 + nK[g + 16 + (lane & 15)];
          prod[r] = (aq0[m][r] + qb0) * k0v + (aq1[m][r] + qb1) * k1v;
        }
        #pragma unroll
        for (int mm = 1; mm < 16; mm <<= 1) {
          #pragma unroll
          for (int r = 0; r < 4; ++r) prod[r] += __shfl_xor(prod[r], mm, 64);
        }
        if ((lane & 15) == 0) {
          #pragma unroll
          for (int r = 0; r < 4; ++r)
            sc[h * 96 + mt * 16 + ((lane >> 4) << 2) + r] = prod[r];
        }
      }
    }
  }

  // ---- Phase B MFMA + nV fold (all independent of sc) ----
  const f32x4 z = {0.f, 0.f, 0.f, 0.f};
  f32x4 accB[6][2] = {{z, z}, {z, z}, {z, z}, {z, z}, {z, z}, {z, z}};
  const int col0 = wid * 16 + (lane & 15), col1 = col0 + 128;
  const int h0 = col0 >> 5, cc0 = col0 & 31;
  const int h1 = col1 >> 5, cc1 = col1 & 31;
  {
    const unsigned short* wb0 = WeF + ((32 + wid) * 64 + lane) * 8;
    const unsigned short* wb1 = WeF + ((40 + wid) * 64 + lane) * 8;
    __builtin_amdgcn_s_setprio(1);
    for (int kt = 0; kt < 8; ++kt) {
      const bf16x8 b0 = *(const bf16x8*)(wb0 + kt * 24576);
      const bf16x8 b1 = *(const bf16x8*)(wb1 + kt * 24576);
      #pragma unroll
      for (int mt = 0; mt < 6; ++mt) {
        const bf16x8 afr = *(const bf16x8*)(Elds + (mt * 16 + (lane & 15)) * LDE
                                            + ((lane >> 4) << 3) + kt * 32);
        accB[mt][0] = MFMA(afr, b0, accB[mt][0]);
        accB[mt][1] = MFMA(afr, b1, accB[mt][1]);
      }
    }
    __builtin_amdgcn_s_setprio(0);
    const float base0 = bias[512 + col0], base1 = bias[512 + col1];
    #pragma unroll
    for (int mt = 0; mt < 6; ++mt) {
      #pragma unroll
      for (int r = 0; r < 4; ++r) {
        const int j = mt * 16 + ((lane >> 4) << 2) + r;
        accB[mt][0][r] += base0 + nV[((b * 8 + h0) * 96 + j) * 32 + cc0];
        accB[mt][1][r] += base1 + nV[((b * 8 + h1) * 96 + j) * 32 + cc1];
      }
    }
  }

  // ---- softmax (wave-local) ----
  {
    const int h = wid;
    const float s0 = sc[h * 96 + lane] * SCALE;
    const float s1 = (lane < 32) ? sc[h * 96 + 64 + lane] * SCALE : -1e30f;
    float mx = fmaxf(s0, s1);
    #pragma unroll
    for (int m = 1; m < 64; m <<= 1) mx = fmaxf(mx, __shfl_xor(mx, m, 64));
    const float e0 = __expf(s0 - mx);
    const float e1 = (lane < 32) ? __expf(s1 - mx) : 0.f;
    float sm = e0 + e1;
    #pragma unroll
    for (int m = 1; m < 64; m <<= 1) sm += __shfl_xor(sm, m, 64);
    const float inv = 1.f / sm;
    sc[h * 96 + lane] = e0 * inv;
    if (lane < 32) sc[h * 96 + 64 + lane] = e1 * inv;
  }
  __syncthreads();                                   // bar2: attn published

  // ---- epilogue: nn = sum_j attn * accB ----
  {
    float nn[2] = {0.f, 0.f};
    #pragma unroll
    for (int mt = 0; mt < 6; ++mt) {
      #pragma unroll
      for (int r = 0; r < 4; ++r) {
        const int j = mt * 16 + ((lane >> 4) << 2) + r;
        nn[0] += sc[h0 * 96 + j] * accB[mt][0][r];
        nn[1] += sc[h1 * 96 + j] * accB[mt][1][r];
      }
    }
    #pragma unroll
    for (int s = 0; s < 2; ++s) {
      nn[s] += __shfl_xor(nn[s], 16, 64);
      nn[s] += __shfl_xor(nn[s], 32, 64);
    }
    if (lane < 16) {
      attw[bi * 256 + wid * 16 + lane] = nn[0];
      attw[bi * 256 + (wid + 8) * 16 + lane] = nn[1];
    }
  }
}

// ---------------------------------------------------------------------------
// K3: node tail. 96 blocks (row-tile x ps). NL1 -> NL2+LN -> one proj set.
// ---------------------------------------------------------------------------
__global__ __launch_bounds__(256)
void node_tail(const float* __restrict__ attw, const float* __restrict__ node,
               const unsigned short* __restrict__ NL1F, const float* __restrict__ B1,
               const unsigned short* __restrict__ NL2F, const float* __restrict__ B2,
               const float* __restrict__ g, const float* __restrict__ be,
               const unsigned short* __restrict__ Wn1F, const float* __restrict__ P1b,
               const unsigned short* __restrict__ Wn2F, const float* __restrict__ P2b,
               float* __restrict__ node_out,
               float* __restrict__ n1Q, float* __restrict__ n1K, float* __restrict__ n1V,
               float* __restrict__ n2Q, float* __restrict__ n2K, float* __restrict__ n2V)
{
  __shared__ unsigned short Xl[16 * LDE];     // attw -> LN out
  __shared__ unsigned short Hl[16 * LDE];     // relu hidden
  __shared__ float bb[1024];                  // B1|B2|g|be
  __shared__ float psum[4][16], psq[4][16];
  __shared__ float statm[16], statr[16];

  const int t = threadIdx.x, lane = t & 63, w = t >> 6;
  const int ps = blockIdx.x & 1, rb = blockIdx.x >> 1;
  const int r0 = rb * 16, b = rb / 6, nbase = (rb % 6) * 16;

  bb[t] = B1[t]; bb[256 + t] = B2[t]; bb[512 + t] = g[t]; bb[768 + t] = be[t];

  for (int u = t; u < 16 * 64; u += 256) {
    const int j = u >> 6, gg = u & 63;
    const float4 v = *(const float4*)(attw + (size_t)(r0 + j) * 256 + gg * 4);
    const unsigned lo = (unsigned)f2bf(v.x) | ((unsigned)f2bf(v.y) << 16);
    const unsigned hi = (unsigned)f2bf(v.z) | ((unsigned)f2bf(v.w) << 16);
    *(uint2*)(Xl + j * LDE + gg * 4) = make_uint2(lo, hi);
  }
  __syncthreads();                                   // bar1

  const f32x4 z = {0.f, 0.f, 0.f, 0.f};

  // ---- NL1 + relu -> Hl ----
  {
    f32x4 a1[4] = {z, z, z, z};
    for (int kt = 0; kt < 8; ++kt) {
      const bf16x8 afr = *(const bf16x8*)(Xl + (lane & 15) * LDE + ((lane >> 4) << 3) + kt * 32);
      #pragma unroll
      for (int p = 0; p < 4; ++p) {
        const bf16x8 bf = *(const bf16x8*)(NL1F + (((kt << 4) + (w * 4 + p)) * 64 + lane) * 8);
        a1[p] = MFMA(afr, bf, a1[p]);
      }
    }
    #pragma unroll
    for (int p = 0; p < 4; ++p) {
      const int col = (w * 4 + p) * 16 + (lane & 15);
      const float bv = bb[col];
      #pragma unroll
      for (int r = 0; r < 4; ++r) {
        const int j = ((lane >> 4) << 2) + r;
        Hl[j * LDE + col] = f2bf(fmaxf(a1[p][r] + bv, 0.f));
      }
    }
  }
  __syncthreads();                                   // bar2

  // ---- NL2 + residual + LayerNorm -> node_out + Xl ----
  float xv[4][4];
  {
    f32x4 a2[4] = {z, z, z, z};
    for (int kt = 0; kt < 8; ++kt) {
      const bf16x8 afr = *(const bf16x8*)(Hl + (lane & 15) * LDE + ((lane >> 4) << 3) + kt * 32);
      #pragma unroll
      for (int p = 0; p < 4; ++p) {
        const bf16x8 bf = *(const bf16x8*)(NL2F + (((kt << 4) + (w * 4 + p)) * 64 + lane) * 8);
        a2[p] = MFMA(afr, bf, a2[p]);
      }
    }
    #pragma unroll
    for (int p = 0; p < 4; ++p) {
      const int col = (w * 4 + p) * 16 + (lane & 15);
      const float bv = bb[256 + col];
      #pragma unroll
      for (int r = 0; r < 4; ++r) {
        const int j = ((lane >> 4) << 2) + r;
        xv[p][r] = a2[p][r] + bv + node[(size_t)(r0 + j) * 256 + col];
      }
    }
    #pragma unroll
    for (int r = 0; r < 4; ++r) {
      float s = 0.f, q = 0.f;
      #pragma unroll
      for (int p = 0; p < 4; ++p) { s += xv[p][r]; q += xv[p][r] * xv[p][r]; }
      #pragma unroll
      for (int m = 1; m < 16; m <<= 1) { s += __shfl_xor(s, m, 64); q += __shfl_xor(q, m, 64); }
      if ((lane & 15) == 0) {
        const int rl = ((lane >> 4) << 2) + r;
        psum[w][rl] = s; psq[w][rl] = q;
      }
    }
  }
  __syncthreads();                                   // bar3
  if (t < 16) {
    const float s = psum[0][t] + psum[1][t] + psum[2][t] + psum[3][t];
    const float q = psq[0][t] + psq[1][t] + psq[2][t] + psq[3][t];
    const float mean = s * (1.f / 256.f);
    statm[t] = mean;
    statr[t] = rsqrtf(q * (1.f / 256.f) - mean * mean + 1e-5f);
  }
  __syncthreads();                                   // bar4
  #pragma unroll
  for (int p = 0; p < 4; ++p) {
    const int col = (w * 4 + p) * 16 + (lane & 15);
    const float gv = bb[512 + col], bv = bb[768 + col];
    #pragma unroll
    for (int r = 0; r < 4; ++r) {
      const int j = ((lane >> 4) << 2) + r;
      const float o = (xv[p][r] - statm[j]) * statr[j] * gv + bv;
      if (ps == 0) node_out[(size_t)(r0 + j) * 256 + col] = o;
      Xl[j * LDE + col] = f2bf(o);
    }
  }
  __syncthreads();                                   // bar5

  // ---- projections for this block's ps ----
  {
    const unsigned short* WF = ps ? Wn2F : Wn1F;
    const float* pb = ps ? P2b : P1b;
    bf16x8 xfr[8];
    #pragma unroll
    for (int kt = 0; kt < 8; ++kt)
      xfr[kt] = *(const bf16x8*)(Xl + (lane & 15) * LDE + ((lane >> 4) << 3) + kt * 32);
    f32x4 ac[12] = {z, z, z, z, z, z, z, z, z, z, z, z};
    __builtin_amdgcn_s_setprio(1);
    for (int kt = 0; kt < 8; ++kt) {
      #pragma unroll
      for (int m = 0; m < 12; ++m) {
        const int nt = w * 12 + m;
        const bf16x8 bf = *(const bf16x8*)(WF + ((kt * 48 + nt) * 64 + lane) * 8);
        ac[m] = MFMA(xfr[kt], bf, ac[m]);
      }
    }
    __builtin_amdgcn_s_setprio(0);
    #pragma unroll
    for (int m = 0; m < 12; ++m) {
      const int colg = (w * 12 + m) * 16 + (lane & 15);
      const int q = colg >> 8, cn = colg & 255, h = cn >> 5, c = cn & 31;
      float* o = (q == 0) ? (ps ? n2Q : n1Q)
               : (q == 1) ? (ps ? n2K : n1K)
                          : (ps ? n2V : n1V);
      const float bv = pb[colg];
      #pragma unroll
      for (int r = 0; r < 4; ++r) {
        const int j = ((lane >> 4) << 2) + r;
        o[((b * 8 + h) * 96 + nbase + j) * 32 + c] = ac[m][r] + bv;
      }
    }
  }
}

// ---------------------------------------------------------------------------
// K5: fused edge update for one (b,i). 512 threads. LDS 60928 B. 7 barriers.
// LN output written fp32 directly from registers (no LDS staging pass).
// ---------------------------------------------------------------------------
__global__ __launch_bounds__(512, 2)
void edge_update(const float* __restrict__ edge, const float* __restrict__ Wee_b,
                 const unsigned short* __restrict__ WeeF,
                 const unsigned short* __restrict__ EL1F,
                 const unsigned short* __restrict__ EL2F,
                 const float* __restrict__ EL1_b, const float* __restrict__ EL2_b,
                 const float* __restrict__ n1Q, const float* __restrict__ n1K, const float* __restrict__ n1V,
                 const float* __restrict__ n2Q, const float* __restrict__ n2K, const float* __restrict__ n2V,
                 const float* __restrict__ lng, const float* __restrict__ lnb,
                 float* __restrict__ edge_out)
{
  __shared__ unsigned short Elds[96 * LDE];   // 50688 B (E -> attw_e -> hidden)
  __shared__ float se[768];                   // silu(scores); later psum[8][96]
  __shared__ float bn1[768];                  // Wee_b + n1p;  later psq[8][96]
  __shared__ float b12[512];                  // EL1|EL2 bias; [0..191] later stats
  __shared__ float lg[256], lb[256];          // 2048 B

  const int tid = threadIdx.x, lane = tid & 63, wid = tid >> 6;
  const int b = blockIdx.x & 7, i = blockIdx.x >> 3;
  const size_t bi = (size_t)(b * 96 + i);

  for (int u = tid; u < 768; u += 512) {
    const int q = u >> 8, cn = u & 255, h = cn >> 5, c = cn & 31;
    const float* s = (q == 0) ? n1Q : (q == 1) ? n1K : n1V;
    bn1[u] = Wee_b[u] + s[((b * 8 + h) * 96 + i) * 32 + c];
  }
  b12[tid] = (tid < 256) ? EL1_b[tid] : EL2_b[tid - 256];
  if (tid < 256) { lg[tid] = lng[tid]; lb[tid] = lnb[tid]; }

  const float* Erow = edge + bi * 24576;
  for (int u = tid; u < 96 * 64; u += 512) {
    const int j = u >> 6, g = u & 63;
    const float4 v = *(const float4*)(Erow + j * 256 + g * 4);
    const unsigned lo = (unsigned)f2bf(v.x) | ((unsigned)f2bf(v.y) << 16);
    const unsigned hi = (unsigned)f2bf(v.z) | ((unsigned)f2bf(v.w) << 16);
    *(uint2*)(Elds + j * LDE + g * 4) = make_uint2(lo, hi);
  }
  __syncthreads();                                   // bar1: E staged

  // ---- Phase A: head h = wid; 2 passes x 3 mt; silu at write ----
  {
    const int h = wid;
    const unsigned short* wq0 = WeeF + ((2 * h) * 64 + lane) * 8;
    const unsigned short* wq1 = WeeF + ((2 * h + 1) * 64 + lane) * 8;
    const unsigned short* wk0 = WeeF + ((16 + 2 * h) * 64 + lane) * 8;
    const unsigned short* wk1 = WeeF + ((17 + 2 * h) * 64 + lane) * 8;
    const int c0 = h * 32 + (lane & 15), c1 = c0 + 16;
    const float qb0 = bn1[c0], qb1 = bn1[c1];
    const float kb0 = bn1[256 + c0], kb1 = bn1[256 + c1];
    for (int pass = 0; pass < 2; ++pass) {
      const f32x4 z = {0.f, 0.f, 0.f, 0.f};
      f32x4 aq0[3] = {z, z, z}, aq1[3] = {z, z, z}, ak0[3] = {z, z, z}, ak1[3] = {z, z, z};
      __builtin_amdgcn_s_setprio(1);
      for (int kt = 0; kt < 8; ++kt) {
        const bf16x8 b0 = *(const bf16x8*)(wq0 + kt * 24576);
        const bf16x8 b1 = *(const bf16x8*)(wq1 + kt * 24576);
        const bf16x8 b2 = *(const bf16x8*)(wk0 + kt * 24576);
        const bf16x8 b3 = *(const bf16x8*)(wk1 + kt * 24576);
        #pragma unroll
        for (int m = 0; m < 3; ++m) {
          const int mt = pass * 3 + m;
          const bf16x8 afr = *(const bf16x8*)(Elds + (mt * 16 + (lane & 15)) * LDE
                                              + ((lane >> 4) << 3) + kt * 32);
          aq0[m] = MFMA(afr, b0, aq0[m]);
          aq1[m] = MFMA(afr, b1, aq1[m]);
          ak0[m] = MFMA(afr, b2, ak0[m]);
          ak1[m] = MFMA(afr, b3, ak1[m]);
        }
      }
      __builtin_amdgcn_s_setprio(0);
      #pragma unroll
      for (int m = 0; m < 3; ++m) {
        const int mt = pass * 3 + m;
        float prod[4];
        #pragma unroll
        for (int r = 0; r < 4; ++r) {
          const int j = mt * 16 + ((lane >> 4) << 2) + r;
          const int g = ((b * 8 + h) * 96 + j) * 32;
          const float q0v = aq0[m][r] + qb0 + n2Q[g + (lane & 15)];
          const float q1v = aq1[m][r] + qb1 + n2Q[g + 16 + (lane & 15)];
          const float k0v = ak0[m][r] + kb0 + n2K[g + (lane & 15)];
          const float k1v = ak1[m][r] + kb1 + n2K[g + 16 + (lane & 15)];
          prod[r] = q0v * k0v + q1v * k1v;
        }
        #pragma unroll
        for (int mm = 1; mm < 16; mm <<= 1) {
          #pragma unroll
          for (int r = 0; r < 4; ++r) prod[r] += __shfl_xor(prod[r], mm, 64);
        }
        if ((lane & 15) == 0) {
          #pragma unroll
          for (int r = 0; r < 4; ++r) {
            const float d = prod[r] * SCALE;
            se[h * 96 + mt * 16 + ((lane >> 4) << 2) + r] = d / (1.f + __expf(-d));
          }
        }
      }
    }
  }

  // ---- Phase B MFMA + n2V fold (independent of se) before the barrier ----
  const f32x4 z = {0.f, 0.f, 0.f, 0.f};
  f32x4 acc[6][2] = {{z, z}, {z, z}, {z, z}, {z, z}, {z, z}, {z, z}};
  const int col0 = wid * 16 + (lane & 15), col1 = col0 + 128;
  {
    const int h0 = col0 >> 5, cc0 = col0 & 31;
    const int h1 = col1 >> 5, cc1 = col1 & 31;
    const unsigned short* wb0 = WeeF + ((32 + wid) * 64 + lane) * 8;
    const unsigned short* wb1 = WeeF + ((40 + wid) * 64 + lane) * 8;
    __builtin_amdgcn_s_setprio(1);
    for (int kt = 0; kt < 8; ++kt) {
      const bf16x8 b0 = *(const bf16x8*)(wb0 + kt * 24576);
      const bf16x8 b1 = *(const bf16x8*)(wb1 + kt * 24576);
      #pragma unroll
      for (int mt = 0; mt < 6; ++mt) {
        const bf16x8 afr = *(const bf16x8*)(Elds + (mt * 16 + (lane & 15)) * LDE
                                            + ((lane >> 4) << 3) + kt * 32);
        acc[mt][0] = MFMA(afr, b0, acc[mt][0]);
        acc[mt][1] = MFMA(afr, b1, acc[mt][1]);
      }
    }
    __builtin_amdgcn_s_setprio(0);
    const float base0 = bn1[512 + col0], base1 = bn1[512 + col1];
    #pragma unroll
    for (int mt = 0; mt < 6; ++mt) {
      #pragma unroll
      for (int r = 0; r < 4; ++r) {
        const int j = mt * 16 + ((lane >> 4) << 2) + r;
        acc[mt][0][r] += base0 + n2V[((b * 8 + h0) * 96 + j) * 32 + cc0];
        acc[mt][1][r] += base1 + n2V[((b * 8 + h1) * 96 + j) * 32 + cc1];
      }
    }
  }
  __syncthreads();                                   // bar2: se done + E reads done

  // ---- Phase B epilogue: attw_e = silu * acc, write in place ----
  {
    const int h0 = col0 >> 5, h1 = col1 >> 5;
    #pragma unroll
    for (int mt = 0; mt < 6; ++mt) {
      #pragma unroll
      for (int r = 0; r < 4; ++r) {
        const int j = mt * 16 + ((lane >> 4) << 2) + r;
        Elds[j * LDE + col0] = f2bf(se[h0 * 96 + j] * acc[mt][0][r]);
        Elds[j * LDE + col1] = f2bf(se[h1 * 96 + j] * acc[mt][1][r]);
      }
    }
  }
  __syncthreads();                                   // bar3: attw_e published

  // ---- EL1 + relu (kt-outer), in place ----
  {
    #pragma unroll
    for (int mt = 0; mt < 6; ++mt) { acc[mt][0] = z; acc[mt][1] = z; }
    const unsigned short* wb0 = EL1F + (wid * 64 + lane) * 8;
    const unsigned short* wb1 = EL1F + ((wid + 8) * 64 + lane) * 8;
    __builtin_amdgcn_s_setprio(1);
    for (int kt = 0; kt < 8; ++kt) {
      const bf16x8 b0 = *(const bf16x8*)(wb0 + kt * 8192);
      const bf16x8 b1 = *(const bf16x8*)(wb1 + kt * 8192);
      #pragma unroll
      for (int mt = 0; mt < 6; ++mt) {
        const bf16x8 afr = *(const bf16x8*)(Elds + (mt * 16 + (lane & 15)) * LDE
                                            + ((lane >> 4) << 3) + kt * 32);
        acc[mt][0] = MFMA(afr, b0, acc[mt][0]);
        acc[mt][1] = MFMA(afr, b1, acc[mt][1]);
      }
    }
    __builtin_amdgcn_s_setprio(0);
    __syncthreads();                                 // bar4: attw_e reads done
    const float bv0 = b12[col0], bv1 = b12[col1];
    #pragma unroll
    for (int mt = 0; mt < 6; ++mt) {
      #pragma unroll
      for (int r = 0; r < 4; ++r) {
        const int j = mt * 16 + ((lane >> 4) << 2) + r;
        Elds[j * LDE + col0] = f2bf(fmaxf(acc[mt][0][r] + bv0, 0.f));
        Elds[j * LDE + col1] = f2bf(fmaxf(acc[mt][1][r] + bv1, 0.f));
      }
    }
  }
  __syncthreads();                                   // bar5: hidden published

  // ---- EL2 (kt-outer) + residual + batched LayerNorm -> direct fp32 out ----
  {
    #pragma unroll
    for (int mt = 0; mt < 6; ++mt) { acc[mt][0] = z; acc[mt][1] = z; }
    const unsigned short* wb0 = EL2F + (wid * 64 + lane) * 8;
    const unsigned short* wb1 = EL2F + ((wid + 8) * 64 + lane) * 8;
    __builtin_amdgcn_s_setprio(1);
    for (int kt = 0; kt < 8; ++kt) {
      const bf16x8 b0 = *(const bf16x8*)(wb0 + kt * 8192);
      const bf16x8 b1 = *(const bf16x8*)(wb1 + kt * 8192);
      #pragma unroll
      for (int mt = 0; mt < 6; ++mt) {
        const bf16x8 afr = *(const bf16x8*)(Elds + (mt * 16 + (lane & 15)) * LDE
                                            + ((lane >> 4) << 3) + kt * 32);
        acc[mt][0] = MFMA(afr, b0, acc[mt][0]);
        acc[mt][1] = MFMA(afr, b1, acc[mt][1]);
      }
    }
    __builtin_amdgcn_s_setprio(0);
    const float bv0 = b12[256 + col0], bv1 = b12[256 + col1];
    const float g0 = lg[col0], g1 = lg[col1], be0 = lb[col0], be1 = lb[col1];
    // residual adds (regs + global only)
    #pragma unroll
    for (int mt = 0; mt < 6; ++mt) {
      #pragma unroll
      for (int r = 0; r < 4; ++r) {
        const int j = mt * 16 + ((lane >> 4) << 2) + r;
        acc[mt][0][r] += bv0 + Erow[j * 256 + col0];
        acc[mt][1][r] += bv1 + Erow[j * 256 + col1];
      }
    }
    // per-wave partials into se/bn1 (dead since bar3)
    #pragma unroll
    for (int mt = 0; mt < 6; ++mt) {
      #pragma unroll
      for (int r = 0; r < 4; ++r) {
        float s = acc[mt][0][r] + acc[mt][1][r];
        float q = acc[mt][0][r] * acc[mt][0][r] + acc[mt][1][r] * acc[mt][1][r];
        #pragma unroll
        for (int m = 1; m < 16; m <<= 1) { s += __shfl_xor(s, m, 64); q += __shfl_xor(q, m, 64); }
        if ((lane & 15) == 0) {
          const int j = mt * 16 + ((lane >> 4) << 2) + r;
          se[wid * 96 + j] = s; bn1[wid * 96 + j] = q;
        }
      }
    }
    __syncthreads();                                 // bar6: partials published
    if (tid < 96) {
      float s = 0.f, q = 0.f;
      #pragma unroll
      for (int w = 0; w < 8; ++w) { s += se[w * 96 + tid]; q += bn1[w * 96 + tid]; }
      const float mean = s * (1.f / 256.f);
      b12[tid] = mean;
      b12[96 + tid] = rsqrtf(q * (1.f / 256.f) - mean * mean + 1e-5f);
    }
    __syncthreads();                                 // bar7: stats published
    float* orow = edge_out + bi * 24576;
    #pragma unroll
    for (int mt = 0; mt < 6; ++mt) {
      #pragma unroll
      for (int r = 0; r < 4; ++r) {
        const int j = mt * 16 + ((lane >> 4) << 2) + r;
        const float mean = b12[j], rs = b12[96 + j];
        orow[j * 256 + col0] = (acc[mt][0][r] - mean) * rs * g0 + be0;
        orow[j * 256 + col1] = (acc[mt][1][r] - mean) * rs * g1 + be1;
      }
    }
  }
}

// ---------------------------------------------------------------------------
extern "C" void kernel_launch(void* const* d_in, const int* in_sizes, int n_in,
                              void* d_out, int out_size, void* d_ws, size_t ws_size,
                              hipStream_t stream)
{
  (void)in_sizes; (void)n_in; (void)out_size; (void)ws_size;

  const float* node   = (const float*)d_in[0];
  const float* edge   = (const float*)d_in[1];
  const float* Wn_w   = (const float*)d_in[2];
  const float* Wn_b   = (const float*)d_in[3];
  const float* We_w   = (const float*)d_in[4];
  const float* We_b   = (const float*)d_in[5];
  const float* Wn1_w  = (const float*)d_in[6];
  const float* Wn1_b  = (const float*)d_in[7];
  const float* Wn2_w  = (const float*)d_in[8];
  const float* Wn2_b  = (const float*)d_in[9];
  const float* Wee_w  = (const float*)d_in[10];
  const float* Wee_b  = (const float*)d_in[11];
  const float* NL1_w  = (const float*)d_in[12];
  const float* NL1_b  = (const float*)d_in[13];
  const float* NL2_w  = (const float*)d_in[14];
  const float* NL2_b  = (const float*)d_in[15];
  const float* EL1_w  = (const float*)d_in[16];
  const float* EL1_b  = (const float*)d_in[17];
  const float* EL2_w  = (const float*)d_in[18];
  const float* EL2_b  = (const float*)d_in[19];
  const float* NLN1_g = (const float*)d_in[20];
  const float* NLN1_b = (const float*)d_in[21];
  const float* ELN1_g = (const float*)d_in[22];
  const float* ELN1_b = (const float*)d_in[23];

  float* out = (float*)d_out;
  float* node_out = out;               // [8,96,256]
  float* edge_out = out + 196608;      // [8,96,96,256]

  float* wsf = (float*)d_ws;
  float* nQ  = wsf;                float* nK  = wsf + 196608;   float* nV  = wsf + 393216;
  float* n1Q = wsf + 589824;       float* n1K = wsf + 786432;   float* n1V = wsf + 983040;
  float* n2Q = wsf + 1179648;      float* n2K = wsf + 1376256;  float* n2V = wsf + 1572864;
  float* attw = wsf + 1769472;
  unsigned short* fb   = (unsigned short*)(wsf + 1966080);
  unsigned short* WeF  = fb;                 // 196608
  unsigned short* WeeF = fb + 196608;        // 196608
  unsigned short* EL1F = fb + 393216;        // 65536
  unsigned short* EL2F = fb + 458752;        // 65536
  unsigned short* NL1F = fb + 524288;        // 65536
  unsigned short* NL2F = fb + 589824;        // 65536
  unsigned short* Wn1F = fb + 655360;        // 196608
  unsigned short* Wn2F = fb + 851968;        // 196608
  unsigned short* WnF  = fb + 1048576;       // 196608

  prep_frags<<<152, 256, 0, stream>>>(We_w, Wee_w, EL1_w, EL2_w, NL1_w, NL2_w,
                                      Wn1_w, Wn2_w, Wn_w, fb);
  node_qkv<<<48, 256, 0, stream>>>(node, WnF, Wn_b, nQ, nK, nV);
  node_attn<<<768, 512, 0, stream>>>(edge, We_b, WeF, nQ, nK, nV, attw);
  node_tail<<<96, 256, 0, stream>>>(attw, node, NL1F, NL1_b, NL2F, NL2_b,
                                    NLN1_g, NLN1_b, Wn1F, Wn1_b, Wn2F, Wn2_b,
                                    node_out, n1Q, n1K, n1V, n2Q, n2K, n2V);
  edge_update<<<768, 512, 0, stream>>>(edge, Wee_b, WeeF, EL1F, EL2F,
                                       EL1_b, EL2_b, n1Q, n1K, n1V,
                                       n2Q, n2K, n2V, ELN1_g, ELN1_b, edge_out);
}